// Round 18
// baseline (1271.704 us; speedup 1.0000x reference)
//
#include <hip/hip_runtime.h>

typedef unsigned short ushort_t;
typedef unsigned long long u64;
typedef __attribute__((ext_vector_type(8))) short short8;
typedef __attribute__((ext_vector_type(4))) float f32x4;
typedef __attribute__((ext_vector_type(4))) int i32x4;

#define SEQ 512
#define HID 1024
#define GCOLS 4096           // 4*HID
#define HSEQ_ELEMS 16777216  // SEQ*BATCH*HID
#define NWG 128              // 64 col-groups x 2 batch-halves

__device__ __forceinline__ ushort_t f2bf(float f) {
    unsigned u = __float_as_uint(f);
    unsigned r = (u + 0x7FFFu + ((u >> 16) & 1u)) >> 16;
    return (ushort_t)r;
}
__device__ __forceinline__ float bf2f(ushort_t u) {
    return __uint_as_float(((unsigned)u) << 16);
}
__device__ __forceinline__ float sigmoidf_(float x) { return 1.f / (1.f + __expf(-x)); }
__device__ __forceinline__ float tanhs_(float x) {
    float ax = fabsf(x);
    float e  = __expf(-2.f * ax);
    float t  = (1.f - e) / (1.f + e);
    return copysignf(t, x);
}

// 16B coherent (device-scope) load at the L3 coherence point.
__device__ __forceinline__ void ld_h16(i32x4* dst, const ushort_t* p) {
    asm volatile("global_load_dwordx4 %0, %1, off sc0 sc1"
                 : "=&v"(*dst) : "v"(p) : "memory");
}
// 2B coherent tagged publish store (byte-enable merge at L3; no tearing across threads)
__device__ __forceinline__ void st_h2(ushort_t* p, unsigned v) {
    asm volatile("global_store_short %0, %1, off sc0 sc1"
                 :: "v"(p), "v"(v) : "memory");
}

// async global->LDS, 16B per lane (dest = wave-uniform base + lane*16)
__device__ __forceinline__ void gload_lds16(const ushort_t* g, ushort_t* l) {
    __builtin_amdgcn_global_load_lds(
        (const __attribute__((address_space(1))) unsigned*)g,
        (__attribute__((address_space(3))) unsigned*)l, 16, 0, 0);
}

// ---------------- fused prep: convert x (blocks 0..8191) + transpose U/V (8192..16383) ----
__global__ __launch_bounds__(256) void k_prep(
    const float* __restrict__ x, ushort_t* __restrict__ xbf,
    const float* __restrict__ u0, const float* __restrict__ u1, const float* __restrict__ u2, const float* __restrict__ u3,
    const float* __restrict__ v0, const float* __restrict__ v1, const float* __restrict__ v2, const float* __restrict__ v3,
    ushort_t* __restrict__ UT, ushort_t* __restrict__ VT) {
    __shared__ float tile[32][33];
    if (blockIdx.x < 8192) {
        size_t i = ((size_t)blockIdx.x * 256 + threadIdx.x) * 8;
        float4 a = *(const float4*)(x + i);
        float4 b = *(const float4*)(x + i + 4);
        short8 v;
        v[0] = (short)f2bf(a.x); v[1] = (short)f2bf(a.y); v[2] = (short)f2bf(a.z); v[3] = (short)f2bf(a.w);
        v[4] = (short)f2bf(b.x); v[5] = (short)f2bf(b.y); v[6] = (short)f2bf(b.z); v[7] = (short)f2bf(b.w);
        *(short8*)(xbf + i) = v;
        return;
    }
    int bid = blockIdx.x - 8192;
    int m  = bid >> 10;    // matrix 0..7
    int tl = bid & 1023;
    int tr = tl >> 5, tc = tl & 31;
    const float* src = (m == 0) ? u0 : (m == 1) ? u1 : (m == 2) ? u2 : (m == 3) ? u3
                      : (m == 4) ? v0 : (m == 5) ? v1 : (m == 6) ? v2 : v3;
    int r = threadIdx.x >> 5, c = threadIdx.x & 31;
    int k0 = tr * 32, n0 = tc * 32;
#pragma unroll
    for (int i = 0; i < 4; ++i)
        tile[r + 8 * i][c] = src[(size_t)(k0 + r + 8 * i) * HID + n0 + c];
    __syncthreads();
    ushort_t* dst = (m < 4) ? (UT + (size_t)m * HID * HID) : (VT + (size_t)(m - 4) * HID * HID);
#pragma unroll
    for (int i = 0; i < 4; ++i) {
        int row = r + 8 * i;
        dst[(size_t)(n0 + row) * HID + k0 + c] = f2bf(tile[c][row]);
    }
}

// ---------------- phase-1 GEMM: gates_pre = x_bf @ U + bias ----------------
// m97 structure: global_load_lds width=16 staging, 128x128 tile, BK=64, 2-barrier loop.
// Gates stored with PLAIN stores -> L3-resident for the scan (134MB < 256MB L3).
__global__ __launch_bounds__(256) void k_gemm(
    const ushort_t* __restrict__ A, const ushort_t* __restrict__ Bt,
    const float* __restrict__ pbi, const float* __restrict__ pbf,
    const float* __restrict__ pbc, const float* __restrict__ pbo,
    ushort_t* __restrict__ gates) {
    __shared__ ushort_t As[128 * 64];
    __shared__ ushort_t Bs[128 * 64];
    const int tid = threadIdx.x, lane = tid & 63, wv = tid >> 6;
    const int bm = blockIdx.x & 127, bn = blockIdx.x >> 7;
    const size_t m0 = (size_t)bm * 128;
    const size_t n0 = (size_t)bn * 128;
    const int wm = wv >> 1, wn = wv & 1;
    f32x4 acc[4][4] = {};
    const int rsub = lane >> 3;        // 0..7 row within 8-row chunk
    const int koff = (lane & 7) * 8;   // k element offset

    for (int kt = 0; kt < 16; ++kt) {
        int k0 = kt * 64;
#pragma unroll
        for (int j = 0; j < 4; ++j) {
            int row = wv * 32 + j * 8 + rsub;
            gload_lds16(A  + (m0 + row) * 1024 + k0 + koff, &As[wv * 2048 + j * 512]);
            gload_lds16(Bt + (n0 + row) * 1024 + k0 + koff, &Bs[wv * 2048 + j * 512]);
        }
        __syncthreads();   // compiler drains vmcnt before s_barrier
#pragma unroll
        for (int kk = 0; kk < 64; kk += 32) {
            short8 af[4], bfr[4];
            int ko = kk + (lane >> 4) * 8;
#pragma unroll
            for (int mi = 0; mi < 4; ++mi) af[mi] = *(const short8*)(&As[(wm * 64 + mi * 16 + (lane & 15)) * 64 + ko]);
#pragma unroll
            for (int ni = 0; ni < 4; ++ni) bfr[ni] = *(const short8*)(&Bs[(wn * 64 + ni * 16 + (lane & 15)) * 64 + ko]);
#pragma unroll
            for (int mi = 0; mi < 4; ++mi)
#pragma unroll
                for (int ni = 0; ni < 4; ++ni)
                    acc[mi][ni] = __builtin_amdgcn_mfma_f32_16x16x32_bf16(af[mi], bfr[ni], acc[mi][ni], 0, 0, 0);
        }
        __syncthreads();
    }
    const int g = (int)(n0 >> 10);
    const float* bias = (g == 0) ? pbi : (g == 1) ? pbf : (g == 2) ? pbc : pbo;
#pragma unroll
    for (int ni = 0; ni < 4; ++ni) {
        int col = (int)n0 + wn * 64 + ni * 16 + (lane & 15);
        float bv = bias[col & 1023];
#pragma unroll
        for (int mi = 0; mi < 4; ++mi) {
            int row0 = (int)m0 + wm * 64 + mi * 16 + ((lane >> 4) << 2);
#pragma unroll
            for (int r = 0; r < 4; ++r)
                gates[(size_t)(row0 + r) * GCOLS + col] = f2bf(acc[mi][ni][r] + bv);
        }
    }
}

// ---------------- persistent scan: 128 WGs (64 colgroups x 2 batch-halves) x 256 thr ----
// BARRIER-FREE dataflow with TAGGED-BF16 h (R12-R16). ONE change vs R16:
// s_sleep(8) (~210ns) BEFORE the first poll round — consumers currently poll nearly
// synchronously with producers' publish and round 1 almost always misses (publish
// L3-visibility ~0.3-0.5us), costing a full extra round (~0.55us). The pre-poll
// delay converts the typical 2-round detect into sleep + 1 round.
__global__ __launch_bounds__(256, 1) void k_scan(
    const ushort_t* __restrict__ gates, const ushort_t* __restrict__ VT,
    ushort_t* hbuf, float* __restrict__ out) {
    __shared__ float red[2][4 * 1024];                         // 2 x 16KB
    const int tid = threadIdx.x, w = blockIdx.x;
    const int lane = tid & 63, wv = tid >> 6;
    const int q = lane >> 4;          // k-sub selector
    const int arow = lane & 15;       // batch row within half / V row within n-tile
    const int cg = w >> 1;            // col-group 0..63 (16 hidden cols)
    const int bh = w & 1;             // batch half

    // ---- V fragments: 4 gates x 8 k-steps, pinned in 128 VGPRs ----
    short8 bv[4][8];
#pragma unroll
    for (int g = 0; g < 4; ++g) {
        const ushort_t* vrow = VT + ((size_t)(g * 1024 + cg * 16 + arow)) * 1024 + wv * 256 + q * 8;
#pragma unroll
        for (int ks = 0; ks < 8; ++ks)
            bv[g][ks] = *(const short8*)(vrow + ks * 32);
    }

    const int bl = tid >> 4, hcl = tid & 15;          // thread's (batch_local, col_local)
    const int batch_g = bh * 16 + bl;
    const int col_g = cg * 16 + hcl;
    // publish slot (ushort index) in blocked layout [kchunk][batch][8 cols]
    const int pub_idx = ((col_g >> 3) * 32 + batch_g) * 8 + (col_g & 7);
    // this thread's tag bit position: even col carries bit0, odd col carries bit1
    const int tag_sel = col_g & 1;

    // prefetch gates t=0 (plain cached loads; gates are L3-resident)
    float cur[4];
    {
        size_t r0 = (size_t)batch_g * GCOLS + col_g;
#pragma unroll
        for (int g = 0; g < 4; ++g) cur[g] = bf2f(gates[r0 + g * 1024]);
    }

    float c_reg = 0.f;
    for (int t = 0; t < SEQ; ++t) {
        // re-pin V each iteration: forces residency
#pragma unroll
        for (int g = 0; g < 4; ++g)
#pragma unroll
            for (int ks = 0; ks < 8; ++ks)
                asm volatile("" : "+v"(*(i32x4*)&bv[g][ks]));

        const ushort_t* hc = hbuf + (t & 1) * 32768;

        // ---- prefetch gates for t+1 BEFORE the poll: L3-resident (~300ns), fully
        //      drained by the poll's first vmcnt(0) ----
        ushort_t pf[4];
        {
            int tn = (t + 1 < SEQ) ? t + 1 : 0;
            size_t r0 = (size_t)(tn * 32 + batch_g) * GCOLS + col_g;
#pragma unroll
            for (int g = 0; g < 4; ++g) pf[g] = gates[r0 + g * 1024];
        }

        f32x4 acc[4] = {};
        i32x4 hb[8];
        if (t > 0) {
            // ---- poll-load h: 8 x 16B blocks; dword valid iff (d & M) == P ----
            const unsigned P = (unsigned)((t & 1) | (((t >> 1) & 1) << 16));
            const unsigned M = 0x00010001u;
            const ushort_t* hbase = hc + ((wv * 32 + q) * 32 + bh * 16 + arow) * 8;
            unsigned stale = 0xFFu;
            bool retry = false;
            __builtin_amdgcn_s_sleep(8);   // pre-poll delay: let publishes reach L3 visibility
            for (;;) {
                if (retry) __builtin_amdgcn_s_sleep(1);   // backoff: reduce L3 storm
#pragma unroll
                for (int bx = 0; bx < 8; ++bx)
                    if (stale & (1u << bx))
                        ld_h16(&hb[bx], hbase + bx * 1024);   // kchunk stride 4
                asm volatile("s_waitcnt vmcnt(0)" ::: "memory");
                __builtin_amdgcn_sched_barrier(0);   // rule #18: pin validation AFTER waitcnt
                unsigned ns = 0;
#pragma unroll
                for (int bx = 0; bx < 8; ++bx)
                    if (stale & (1u << bx)) {
                        unsigned m = ((((unsigned)hb[bx][0]) ^ P) | (((unsigned)hb[bx][1]) ^ P) |
                                      (((unsigned)hb[bx][2]) ^ P) | (((unsigned)hb[bx][3]) ^ P)) & M;
                        if (m) ns |= 1u << bx;
                    }
                stale = ns;
                if (__all(stale == 0)) break;
                retry = true;
            }
            __builtin_amdgcn_sched_barrier(0);

            // ---- MFMA: loaded dwords are the A-fragments directly ----
#pragma unroll
            for (int ks = 0; ks < 8; ++ks) {
                short8 A = __builtin_bit_cast(short8, hb[ks]);
                acc[0] = __builtin_amdgcn_mfma_f32_16x16x32_bf16(A, bv[0][ks], acc[0], 0, 0, 0);
                acc[1] = __builtin_amdgcn_mfma_f32_16x16x32_bf16(A, bv[1][ks], acc[1], 0, 0, 0);
                acc[2] = __builtin_amdgcn_mfma_f32_16x16x32_bf16(A, bv[2][ks], acc[2], 0, 0, 0);
                acc[3] = __builtin_amdgcn_mfma_f32_16x16x32_bf16(A, bv[3][ks], acc[3], 0, 0, 0);
            }
        }

        // ---- red stores into buffer t&1, rotated cols (2-way aliasing = free) ----
        {
            float* rp = &red[t & 1][wv * 1024];
#pragma unroll
            for (int g = 0; g < 4; ++g)
#pragma unroll
                for (int r = 0; r < 4; ++r) {
                    int bb = q * 4 + r;
                    int colrot = (g * 16 + arow + 16 * q) & 63;
                    rp[bb * 64 + colrot] = acc[g][r];
                }
        }
        __syncthreads();   // the ONLY sync per step

        // ---- gather own 4 gate sums + elementwise; publish FIRST, then out store ----
        {
            const float* rb = &red[t & 1][0];
            float s[4];
            int rotbase = 16 * (bl >> 2);
#pragma unroll
            for (int g = 0; g < 4; ++g) {
                int o = bl * 64 + ((g * 16 + hcl + rotbase) & 63);
                s[g] = rb[o] + rb[1024 + o] + rb[2048 + o] + rb[3072 + o] + cur[g];
            }
            c_reg = sigmoidf_(s[1]) * c_reg + sigmoidf_(s[0]) * tanhs_(s[2]);
            float h = sigmoidf_(s[3]) * tanhs_(c_reg);
            if (t < SEQ - 1) {
                // tagged-bf16 publish: LSB = my tag bit of step tag (t+1)&3
                unsigned tg = (unsigned)(t + 1);
                unsigned bit = tag_sel ? ((tg >> 1) & 1u) : (tg & 1u);
                unsigned hv = ((unsigned)f2bf(h) & ~1u) | bit;
                ushort_t* hn = hbuf + (((t & 1) ^ 1) * 32768);
                st_h2(hn + pub_idx, hv);
            }
            __builtin_nontemporal_store(h, &out[(size_t)t * 32768 + batch_g * 1024 + col_g]);
            if (t == SEQ - 1) {
                out[HSEQ_ELEMS + batch_g * 1024 + col_g] = h;
                out[HSEQ_ELEMS + 32768 + batch_g * 1024 + col_g] = c_reg;
                break;
            }
        }
#pragma unroll
        for (int g = 0; g < 4; ++g) cur[g] = bf2f(pf[g]);
    }
}

extern "C" void kernel_launch(void* const* d_in, const int* in_sizes, int n_in,
                              void* d_out, int out_size, void* d_ws, size_t ws_size,
                              hipStream_t stream) {
    const float* x  = (const float*)d_in[0];
    const float* Ui = (const float*)d_in[1];
    const float* Vi = (const float*)d_in[2];
    const float* bi = (const float*)d_in[3];
    const float* Uf = (const float*)d_in[4];
    const float* Vf = (const float*)d_in[5];
    const float* bfp= (const float*)d_in[6];
    const float* Uc = (const float*)d_in[7];
    const float* Vc = (const float*)d_in[8];
    const float* bc = (const float*)d_in[9];
    const float* Uo = (const float*)d_in[10];
    const float* Vo = (const float*)d_in[11];
    const float* bo = (const float*)d_in[12];

    char* ws = (char*)d_ws;
    ushort_t* hbufB = (ushort_t*)(ws + 4096);                 // 131072 B (2 x blocked 32x1024 bf16)
    ushort_t* xbf   = (ushort_t*)(ws + 266240);               // 33554432 B
    ushort_t* UT    = (ushort_t*)(ws + 33820672);             // 8388608 B
    ushort_t* VT    = (ushort_t*)(ws + 42209280);             // 8388608 B
    ushort_t* gates = (ushort_t*)(ws + 50597888);             // 134217728 B

    // poison: buf0 (even steps, tags {0,2}: bit0=0) -> memset 0x01 sets every bf16 LSB=1 (invalid).
    //         buf1 (odd steps, tags {1,3}: bit0=1) -> memset 0x00 sets LSB=0 (invalid).
    hipMemsetAsync(ws + 4096, 0x01, 65536, stream);
    hipMemsetAsync(ws + 4096 + 65536, 0x00, 65536, stream);
    hipLaunchKernelGGL(k_prep, dim3(16384), dim3(256), 0, stream,
                       x, xbf, Ui, Uf, Uc, Uo, Vi, Vf, Vc, Vo, UT, VT);
    hipLaunchKernelGGL(k_gemm, dim3(4096), dim3(256), 0, stream,
                       xbf, UT, bi, bfp, bc, bo, gates);
    hipLaunchKernelGGL(k_scan, dim3(NWG), dim3(256), 0, stream,
                       gates, VT, hbufB, (float*)d_out);
}